// Round 1
// baseline (35.266 us; speedup 1.0000x reference)
//
#include <hip/hip_runtime.h>

// OCDM modulator: per (batch, sym) row of N=64 complex samples:
//   chirped = sym * exp(i*pi*k^2/64)
//   td      = ifft(chirped) * 8
//   out row = [td[48:64], td[0:64]] as 80 (re,im) float pairs
//
// One wave (64 lanes) per row. 64-pt inverse DFT = radix-2 DIF with
// conjugated twiddles, data in registers, butterflies via __shfl_xor.
// Output of DIF at lane l is X[bitrev6(l)]; reorder via 64-entry LDS
// buffer per wave, then coalesced float2 stores.

__global__ __launch_bounds__(256) void ocdm_kernel(
    const float* __restrict__ sym_re,
    const float* __restrict__ sym_im,
    float2* __restrict__ out,
    int n_rows)
{
    const int l = threadIdx.x & 63;          // lane
    const int w = threadIdx.x >> 6;          // wave within block
    const int wave_global = blockIdx.x * (blockDim.x >> 6) + w;
    const int wave_stride = gridDim.x * (blockDim.x >> 6);

    __shared__ float2 lds[4][64];

    // chirp[l]/8 = exp(i*pi*l^2/64)/8 ; l^2 mod 128 (period of exp(i*pi*m/64))
    float cr, ci;
    {
        float f = (float)((l * l) & 127) * (1.0f / 64.0f);
        cr = 0.125f * cospif(f);
        ci = 0.125f * sinpif(f);
    }

    // Per-stage butterfly constants (depend only on lane):
    // lower lane (l&d==0): out = x + p            -> T = 1,  s = +1
    // upper lane          : out = (p - x) * T     -> T = e^{+i*pi*j/d}, s = -1
    const int D[6] = {32, 16, 8, 4, 2, 1};
    float twr[6], twi[6], sg[6];
#pragma unroll
    for (int s = 0; s < 6; ++s) {
        int d = D[s];
        int j = l & (d - 1);
        bool up = (l & d) != 0;
        float f = (float)j / (float)d;
        twr[s] = up ? cospif(f) : 1.0f;
        twi[s] = up ? sinpif(f) : 0.0f;
        sg[s]  = up ? -1.0f : 1.0f;
    }

    const int n = (int)(__brev((unsigned)l) >> 26);  // bitrev6(l): output index held by this lane

    for (int r = wave_global; r < n_rows; r += wave_stride) {
        const int idx = r * 64 + l;
        float srr = sym_re[idx];
        float sii = sym_im[idx];
        // chirp multiply (scale 1/8 folded in)
        float xr = srr * cr - sii * ci;
        float xi = srr * ci + sii * cr;

        // 6-stage radix-2 DIF inverse DFT across lanes
#pragma unroll
        for (int s = 0; s < 6; ++s) {
            float pr = __shfl_xor(xr, D[s]);
            float pi = __shfl_xor(xi, D[s]);
            float ar = fmaf(sg[s], xr, pr);   // lower: x+p, upper: p-x
            float ai = fmaf(sg[s], xi, pi);
            float nr = ar * twr[s] - ai * twi[s];
            float ni = fmaf(ar, twi[s], ai * twr[s]);
            xr = nr;
            xi = ni;
        }

        // lane l holds td[n]; reorder through LDS (intra-wave only)
        lds[w][n] = make_float2(xr, xi);
        asm volatile("s_waitcnt lgkmcnt(0)" ::: "memory");
        float2 v = lds[w][(l + 48) & 63];    // out[t] = td[(t+48) mod 64]

        const long ob = (long)r * 80;
        out[ob + l] = v;                      // t = l  (0..63)
        if (l < 16)
            out[ob + 64 + l] = v;             // t = 64+l duplicates td[48+l]
        // next iteration's lds write is ordered after this read by in-order
        // per-wave DS execution + compiler may-alias ordering
    }
}

extern "C" void kernel_launch(void* const* d_in, const int* in_sizes, int n_in,
                              void* d_out, int out_size, void* d_ws, size_t ws_size,
                              hipStream_t stream) {
    const float* sym_re = (const float*)d_in[0];
    const float* sym_im = (const float*)d_in[1];
    float2* out = (float2*)d_out;

    const int n_rows = in_sizes[0] / 64;     // 256*512 = 131072

    int blocks = (n_rows + 3) / 4;           // 4 waves per block
    if (blocks > 2048) blocks = 2048;        // grid-stride, 8 waves/SIMD
    ocdm_kernel<<<blocks, 256, 0, stream>>>(sym_re, sym_im, out, n_rows);
}

// Round 2
// 30.968 us; speedup vs baseline: 1.1388x; 1.1388x over previous
//
#include <hip/hip_runtime.h>

// OCDM modulator, 4 rows per wave.
// Row of N=64: chirped = sym * exp(i*pi*k^2/64)/  ; td = unnormalized IDFT * 1/8
// out row = [td[48:64], td[0:64]] as 80 (re,im) float pairs.
//
// Decomposition k = 4j+q (j=0..15 lane-in-group, q in-lane):
//   Y_q[m]   = 16-pt inverse DFT across lanes (radix-2 DIF, bitrev4 order)
//   Z_q      = Y_q[m] * e^{+2pi i m q/64}
//   X[m+16s] = sum_q i^{q s} Z_q      (in-lane radix-4)
// Lane l (j=l&15, g=l>>4) handles row g of its 4-row group, holds X[m+16s].
// Reorder + CP via 320-float2/wave LDS buffer laid out as the output stream.

__global__ __launch_bounds__(256) void ocdm_kernel(
    const float4* __restrict__ re4,
    const float4* __restrict__ im4,
    float2* __restrict__ out,
    int n_groups)                       // n_rows / 4
{
    const int l = threadIdx.x & 63;
    const int w = threadIdx.x >> 6;
    const int g = l >> 4;               // row within 4-row group
    const int j = l & 15;               // lane within 16-pt DFT
    const int wave_global = blockIdx.x * (blockDim.x >> 6) + w;
    const int wave_stride = gridDim.x * (blockDim.x >> 6);

    __shared__ float2 lds[4][320];

    // chirp[k]/8, k = 4j+q  (exp(i*pi*k^2/64), k^2 mod 128)
    float ckr[4], cki[4];
#pragma unroll
    for (int q = 0; q < 4; ++q) {
        int k = 4 * j + q;
        float f = (float)((k * k) & 127) * (1.0f / 64.0f);
        ckr[q] = 0.125f * cospif(f);
        cki[q] = 0.125f * sinpif(f);
    }

    // 16-pt inverse DIF stage constants (depend only on j)
    const int D[4] = {8, 4, 2, 1};
    float twr[4], twi[4], sg[4];
#pragma unroll
    for (int s = 0; s < 4; ++s) {
        int d = D[s];
        int jj = j & (d - 1);
        bool up = (j & d) != 0;
        float f = (float)jj / (float)d;
        twr[s] = up ? cospif(f) : 1.0f;
        twi[s] = up ? sinpif(f) : 0.0f;
        sg[s]  = up ? -1.0f : 1.0f;
    }

    const int m = (int)(__brev((unsigned)j) >> 28);   // bitrev4(j)

    // inter-stage twiddles e^{+2pi i m q / 64}, q = 1..3
    float tqr[3], tqi[3];
#pragma unroll
    for (int q = 1; q <= 3; ++q) {
        float f = (float)(m * q) * (1.0f / 32.0f);
        tqr[q - 1] = cospif(f);
        tqi[q - 1] = sinpif(f);
    }

    const int wbase = g * 80;

    for (int r = wave_global; r < n_groups; r += wave_stride) {
        float4 vr = re4[r * 64 + l];
        float4 vi = im4[r * 64 + l];

        float xr[4], xi[4];
        {
            const float rr[4] = {vr.x, vr.y, vr.z, vr.w};
            const float ii[4] = {vi.x, vi.y, vi.z, vi.w};
#pragma unroll
            for (int q = 0; q < 4; ++q) {
                xr[q] = rr[q] * ckr[q] - ii[q] * cki[q];
                xi[q] = fmaf(rr[q], cki[q], ii[q] * ckr[q]);
            }
        }

        // 16-pt inverse DFT across lanes — 4 independent sequences (ILP)
#pragma unroll
        for (int s = 0; s < 4; ++s) {
#pragma unroll
            for (int q = 0; q < 4; ++q) {
                float pr = __shfl_xor(xr[q], D[s]);
                float pi = __shfl_xor(xi[q], D[s]);
                float ar = fmaf(sg[s], xr[q], pr);   // lower: x+p, upper: p-x
                float ai = fmaf(sg[s], xi[q], pi);
                xr[q] = ar * twr[s] - ai * twi[s];
                xi[q] = fmaf(ar, twi[s], ai * twr[s]);
            }
        }

        // twiddle by e^{+2pi i m q/64}
#pragma unroll
        for (int q = 1; q <= 3; ++q) {
            float ar = xr[q] * tqr[q - 1] - xi[q] * tqi[q - 1];
            float ai = fmaf(xr[q], tqi[q - 1], xi[q] * tqr[q - 1]);
            xr[q] = ar; xi[q] = ai;
        }

        // in-lane radix-4 (inverse): X[m+16s]
        float Ar = xr[0] + xr[2], Ai = xi[0] + xi[2];
        float Br = xr[0] - xr[2], Bi = xi[0] - xi[2];
        float Cr = xr[1] + xr[3], Ci = xi[1] + xi[3];
        float Dr = xr[1] - xr[3], Di = xi[1] - xi[3];
        float2 X0 = make_float2(Ar + Cr, Ai + Ci);    // s=0: n=m
        float2 X1 = make_float2(Br - Di, Bi + Dr);    // s=1: n=m+16
        float2 X2 = make_float2(Ar - Cr, Ai - Ci);    // s=2: n=m+32
        float2 X3 = make_float2(Br + Di, Bi - Dr);    // s=3: n=m+48

        // out slot within 4-row chunk for td[n]: (n+16)&63, plus n+16 if n>=48
        lds[w][wbase + m + 16] = X0;
        lds[w][wbase + m + 32] = X1;
        lds[w][wbase + m + 48] = X2;
        lds[w][wbase + m]      = X3;
        lds[w][wbase + m + 64] = X3;                  // cyclic prefix dup
        asm volatile("s_waitcnt lgkmcnt(0)" ::: "memory");

        const long ob = (long)r * 320;
#pragma unroll
        for (int i = 0; i < 5; ++i)
            out[ob + i * 64 + l] = lds[w][i * 64 + l];
        // next iteration's ds_writes are ordered after these ds_reads by
        // in-order per-wave DS execution (same guarantee round-1 relied on)
    }
}

extern "C" void kernel_launch(void* const* d_in, const int* in_sizes, int n_in,
                              void* d_out, int out_size, void* d_ws, size_t ws_size,
                              hipStream_t stream) {
    const float4* re4 = (const float4*)d_in[0];
    const float4* im4 = (const float4*)d_in[1];
    float2* out = (float2*)d_out;

    const int n_rows = in_sizes[0] / 64;     // 131072
    const int n_groups = n_rows / 4;         // 32768

    int blocks = (n_groups + 3) / 4;
    if (blocks > 2048) blocks = 2048;        // 8192 waves, 4 groups each
    ocdm_kernel<<<blocks, 256, 0, stream>>>(re4, im4, out, n_groups);
}

// Round 3
// 29.292 us; speedup vs baseline: 1.2040x; 1.0572x over previous
//
#include <hip/hip_runtime.h>

// OCDM modulator, 8 rows (2×4-row groups) per wave iteration.
// Row of N=64: chirped = sym * exp(i*pi*k^2/64) ; td = unnormalized IDFT * 1/8
// out row = [td[48:64], td[0:64]] as 80 (re,im) float pairs.
//
// Decomposition k = 4j+q (j=0..15 lane-in-group, q in-lane):
//   Y_q[m]   = 16-pt inverse DFT across lanes (radix-2 DIF, m = bitrev4(j))
//   Z_q      = Y_q[m] * e^{+2pi i m q/64}
//   X[m+16s] = sum_q i^{q s} Z_q      (in-lane radix-4)
// Lane l (j=l&15, g=l>>4) handles row g of each 4-row group.
// Both groups' outputs staged in a 640-float2/wave LDS stream laid out
// exactly as the output, then drained with 5 float4 stores per lane.

__global__ __launch_bounds__(256) void ocdm_kernel(
    const float4* __restrict__ re4,
    const float4* __restrict__ im4,
    float4* __restrict__ out4,
    int n_pairs)                        // n_rows / 8
{
    const int l = threadIdx.x & 63;
    const int w = threadIdx.x >> 6;
    const int g = l >> 4;               // row within 4-row group
    const int j = l & 15;               // lane within 16-pt DFT
    const int wave_global = blockIdx.x * (blockDim.x >> 6) + w;
    const int wave_stride = gridDim.x * (blockDim.x >> 6);

    __shared__ float2 lds[4][640];

    // chirp[k]/8, k = 4j+q  (exp(i*pi*k^2/64), k^2 mod 128)
    float ckr[4], cki[4];
#pragma unroll
    for (int q = 0; q < 4; ++q) {
        int k = 4 * j + q;
        float f = (float)((k * k) & 127) * (1.0f / 64.0f);
        ckr[q] = 0.125f * cospif(f);
        cki[q] = 0.125f * sinpif(f);
    }

    // 16-pt inverse DIF stage constants (depend only on j)
    const int D[4] = {8, 4, 2, 1};
    float twr[4], twi[4], sg[4];
#pragma unroll
    for (int s = 0; s < 4; ++s) {
        int d = D[s];
        int jj = j & (d - 1);
        bool up = (j & d) != 0;
        float f = (float)jj / (float)d;
        twr[s] = up ? cospif(f) : 1.0f;
        twi[s] = up ? sinpif(f) : 0.0f;
        sg[s]  = up ? -1.0f : 1.0f;
    }

    const int m = (int)(__brev((unsigned)j) >> 28);   // bitrev4(j)

    // inter-stage twiddles e^{+2pi i m q / 64}, q = 1..3
    float tqr[3], tqi[3];
#pragma unroll
    for (int q = 1; q <= 3; ++q) {
        float f = (float)(m * q) * (1.0f / 32.0f);
        tqr[q - 1] = cospif(f);
        tqi[q - 1] = sinpif(f);
    }

    const int wbase = g * 80;

    // one 4-row group: chirp * IDFT64, permuted store into lds[w][base+...]
    auto fft_group = [&](float4 vr, float4 vi, int base) {
        float xr[4], xi[4];
        {
            const float rr[4] = {vr.x, vr.y, vr.z, vr.w};
            const float ii[4] = {vi.x, vi.y, vi.z, vi.w};
#pragma unroll
            for (int q = 0; q < 4; ++q) {
                xr[q] = rr[q] * ckr[q] - ii[q] * cki[q];
                xi[q] = fmaf(rr[q], cki[q], ii[q] * ckr[q]);
            }
        }

        // 16-pt inverse DFT across lanes — 4 independent sequences (ILP)
#pragma unroll
        for (int s = 0; s < 4; ++s) {
#pragma unroll
            for (int q = 0; q < 4; ++q) {
                float pr = __shfl_xor(xr[q], D[s]);
                float pi = __shfl_xor(xi[q], D[s]);
                float ar = fmaf(sg[s], xr[q], pr);   // lower: x+p, upper: p-x
                float ai = fmaf(sg[s], xi[q], pi);
                xr[q] = ar * twr[s] - ai * twi[s];
                xi[q] = fmaf(ar, twi[s], ai * twr[s]);
            }
        }

        // twiddle by e^{+2pi i m q/64}
#pragma unroll
        for (int q = 1; q <= 3; ++q) {
            float ar = xr[q] * tqr[q - 1] - xi[q] * tqi[q - 1];
            float ai = fmaf(xr[q], tqi[q - 1], xi[q] * tqr[q - 1]);
            xr[q] = ar; xi[q] = ai;
        }

        // in-lane radix-4 (inverse): X[m+16s]
        float Ar = xr[0] + xr[2], Ai = xi[0] + xi[2];
        float Br = xr[0] - xr[2], Bi = xi[0] - xi[2];
        float Cr = xr[1] + xr[3], Ci = xi[1] + xi[3];
        float Dr = xr[1] - xr[3], Di = xi[1] - xi[3];
        float2 X0 = make_float2(Ar + Cr, Ai + Ci);    // n=m
        float2 X1 = make_float2(Br - Di, Bi + Dr);    // n=m+16
        float2 X2 = make_float2(Ar - Cr, Ai - Ci);    // n=m+32
        float2 X3 = make_float2(Br + Di, Bi - Dr);    // n=m+48

        // out slot within 4-row chunk for td[n]: (n+16)&63, plus n+16 if n>=48
        const int b = base + wbase;
        lds[w][b + m + 16] = X0;
        lds[w][b + m + 32] = X1;
        lds[w][b + m + 48] = X2;
        lds[w][b + m]      = X3;
        lds[w][b + m + 64] = X3;                      // cyclic prefix dup
    };

    for (int p = wave_global; p < n_pairs; p += wave_stride) {
        const int rb = p * 2;                         // 4-row group index
        // issue all four 16B loads up front; group-1's latency hides
        // under group-0's FFT
        float4 vr0 = re4[rb * 64 + l];
        float4 vi0 = im4[rb * 64 + l];
        float4 vr1 = re4[(rb + 1) * 64 + l];
        float4 vi1 = im4[(rb + 1) * 64 + l];

        fft_group(vr0, vi0, 0);
        fft_group(vr1, vi1, 320);

        asm volatile("s_waitcnt lgkmcnt(0)" ::: "memory");

        const float4* lsrc = (const float4*)&lds[w][0];
        const long ob = (long)p * 320;
#pragma unroll
        for (int i = 0; i < 5; ++i)
            out4[ob + i * 64 + l] = lsrc[i * 64 + l];
        // next iteration's ds_writes are ordered after these ds_reads by
        // in-order per-wave DS execution
    }
}

extern "C" void kernel_launch(void* const* d_in, const int* in_sizes, int n_in,
                              void* d_out, int out_size, void* d_ws, size_t ws_size,
                              hipStream_t stream) {
    const float4* re4 = (const float4*)d_in[0];
    const float4* im4 = (const float4*)d_in[1];
    float4* out4 = (float4*)d_out;

    const int n_rows = in_sizes[0] / 64;     // 131072
    const int n_pairs = n_rows / 8;          // 16384

    int blocks = (n_pairs + 3) / 4;
    if (blocks > 2048) blocks = 2048;        // 8192 waves, 2 pairs each
    ocdm_kernel<<<blocks, 256, 0, stream>>>(re4, im4, out4, n_pairs);
}